// Round 1
// baseline (250.100 us; speedup 1.0000x reference)
//
#include <hip/hip_runtime.h>
#include <math.h>

#define B 16
#define C 512
#define L 8192
#define P 128
#define LN_EPS 1e-5f

// ---------------- Kernel A: scores[b,l] = sum_c x[b,c,l]*cw[c] + cb ----------------
__global__ void k_scores(const float* __restrict__ x, const float* __restrict__ cw,
                         const float* __restrict__ cb, float* __restrict__ scores) {
    const int b = blockIdx.y;
    const int l = blockIdx.x * blockDim.x + threadIdx.x;
    const float* xb = x + (size_t)b * C * L;
    float acc = cb[0];
    #pragma unroll 8
    for (int c = 0; c < C; ++c) {
        acc += xb[(size_t)c * L + l] * cw[c];
    }
    scores[b * L + l] = acc;
}

// ---------------- Kernel B: softmax over L (per batch) ----------------
__global__ void k_softmax(const float* __restrict__ scores, float* __restrict__ attn) {
    const int b = blockIdx.x;
    const int tid = threadIdx.x;             // 256 threads = 4 waves
    const float* s = scores + b * L;
    __shared__ float red[4];
    __shared__ float bcast;

    // max
    float m = -INFINITY;
    for (int l = tid; l < L; l += 256) m = fmaxf(m, s[l]);
    for (int off = 32; off; off >>= 1) m = fmaxf(m, __shfl_xor(m, off));
    if ((tid & 63) == 0) red[tid >> 6] = m;
    __syncthreads();
    if (tid == 0) bcast = fmaxf(fmaxf(red[0], red[1]), fmaxf(red[2], red[3]));
    __syncthreads();
    const float M = bcast;
    __syncthreads();

    // sum of exp
    float z = 0.f;
    for (int l = tid; l < L; l += 256) z += __expf(s[l] - M);
    for (int off = 32; off; off >>= 1) z += __shfl_xor(z, off);
    if ((tid & 63) == 0) red[tid >> 6] = z;
    __syncthreads();
    if (tid == 0) bcast = red[0] + red[1] + red[2] + red[3];
    __syncthreads();
    const float Zinv = 1.0f / bcast;

    for (int l = tid; l < L; l += 256) {
        attn[b * L + l] = __expf(s[l] - M) * Zinv;
    }
}

// ---------------- Kernel C: context[b,c] = sum_l x[b,c,l]*attn[b,l] ----------------
__global__ void k_context(const float* __restrict__ x, const float* __restrict__ attn,
                          float* __restrict__ ctx) {
    const int c = blockIdx.x;
    const int b = blockIdx.y;
    const float4* xr = (const float4*)(x + ((size_t)b * C + c) * L);
    const float4* ar = (const float4*)(attn + (size_t)b * L);
    float acc = 0.f;
    for (int i = threadIdx.x; i < L / 4; i += 256) {
        float4 xv = xr[i];
        float4 av = ar[i];
        acc += xv.x * av.x + xv.y * av.y + xv.z * av.z + xv.w * av.w;
    }
    for (int off = 32; off; off >>= 1) acc += __shfl_xor(acc, off);
    __shared__ float red[4];
    if ((threadIdx.x & 63) == 0) red[threadIdx.x >> 6] = acc;
    __syncthreads();
    if (threadIdx.x == 0) {
        ctx[b * C + c] = red[0] + red[1] + red[2] + red[3];
    }
}

// ---------------- Kernel D: tiny MLP: t = ReLU(LN(w1@ctx + b1)); add = w2@t + b2 ----
__global__ void k_mlp(const float* __restrict__ ctx, const float* __restrict__ w1,
                      const float* __restrict__ b1, const float* __restrict__ lnw,
                      const float* __restrict__ lnb, const float* __restrict__ w2,
                      const float* __restrict__ b2, float* __restrict__ add_term) {
    const int b = blockIdx.x;
    const int tid = threadIdx.x;           // 128 threads
    __shared__ float sctx[C];
    __shared__ float st[P];

    for (int c = tid; c < C; c += P) sctx[c] = ctx[b * C + c];
    __syncthreads();

    // t[p] = w1[p,:] . ctx + b1[p]
    float acc = b1[tid];
    const float* w1r = w1 + (size_t)tid * C;
    #pragma unroll 4
    for (int c = 0; c < C; ++c) acc += w1r[c] * sctx[c];
    st[tid] = acc;
    __syncthreads();

    // LayerNorm over P (every thread computes mean/var via LDS broadcast reads)
    float mu = 0.f;
    for (int p = 0; p < P; ++p) mu += st[p];
    mu *= (1.0f / P);
    float var = 0.f;
    for (int p = 0; p < P; ++p) { float d = st[p] - mu; var += d * d; }
    var *= (1.0f / P);
    float tval = (acc - mu) * rsqrtf(var + LN_EPS) * lnw[tid] + lnb[tid];
    tval = fmaxf(tval, 0.f);               // ReLU
    __syncthreads();
    st[tid] = tval;
    __syncthreads();

    // add_term[c] = w2[c,:] . t + b2[c]
    for (int c = tid; c < C; c += P) {
        float a = b2[c];
        const float* w2r = w2 + (size_t)c * P;
        #pragma unroll 4
        for (int p = 0; p < P; ++p) a += w2r[p] * st[p];
        add_term[b * C + c] = a;
    }
}

// ---------------- Kernel E: out = x + add_term[:, :, None] ----------------
__global__ void k_add(const float* __restrict__ x, const float* __restrict__ add_term,
                      float* __restrict__ out) {
    const size_t N4 = (size_t)B * C * L / 4;
    const size_t stride = (size_t)gridDim.x * blockDim.x;
    for (size_t i = (size_t)blockIdx.x * blockDim.x + threadIdx.x; i < N4; i += stride) {
        size_t bc = i / (L / 4);
        float at = add_term[bc];
        float4 xv = ((const float4*)x)[i];
        float4 o;
        o.x = xv.x + at; o.y = xv.y + at; o.z = xv.z + at; o.w = xv.w + at;
        ((float4*)out)[i] = o;
    }
}

extern "C" void kernel_launch(void* const* d_in, const int* in_sizes, int n_in,
                              void* d_out, int out_size, void* d_ws, size_t ws_size,
                              hipStream_t stream) {
    const float* x   = (const float*)d_in[0];
    const float* cw  = (const float*)d_in[1];
    const float* cb  = (const float*)d_in[2];
    const float* w1  = (const float*)d_in[3];
    const float* b1  = (const float*)d_in[4];
    const float* lnw = (const float*)d_in[5];
    const float* lnb = (const float*)d_in[6];
    const float* w2  = (const float*)d_in[7];
    const float* b2  = (const float*)d_in[8];
    float* out = (float*)d_out;

    // workspace layout
    char* ws = (char*)d_ws;
    float* scores   = (float*)(ws);                         // B*L floats  (512 KB)
    float* attn     = (float*)(ws + (size_t)B * L * 4);     // B*L floats  (512 KB)
    float* ctx      = (float*)(ws + (size_t)2 * B * L * 4); // B*C floats  (32 KB)
    float* add_term = (float*)(ws + (size_t)2 * B * L * 4 + (size_t)B * C * 4);

    // A: scores
    k_scores<<<dim3(L / 256, B), 256, 0, stream>>>(x, cw, cb, scores);
    // B: softmax
    k_softmax<<<dim3(B), 256, 0, stream>>>(scores, attn);
    // C: context
    k_context<<<dim3(C, B), 256, 0, stream>>>(x, attn, ctx);
    // D: MLP
    k_mlp<<<dim3(B), P, 0, stream>>>(ctx, w1, b1, lnw, lnb, w2, b2, add_term);
    // E: out = x + add_term
    k_add<<<dim3(2048), 256, 0, stream>>>(x, add_term, out);
}

// Round 2
// 209.088 us; speedup vs baseline: 1.1961x; 1.1961x over previous
//
#include <hip/hip_runtime.h>
#include <hip/hip_bf16.h>
#include <math.h>

#define B 16
#define C 512
#define L 8192
#define PP 128
#define TL 32
#define NT (L / TL)        // 256 tiles per batch
#define LN_EPS 1e-5f

// ---- Fused: scores + tile-local softmax + partial context. One x read total. ----
// Block = (b, l-tile of 32). 1024 threads. x tile staged to LDS as bf16.
__global__ __launch_bounds__(1024, 8) void k_fused(
    const float* __restrict__ x, const float* __restrict__ cw,
    float* __restrict__ part_pc, float* __restrict__ part_m, float* __restrict__ part_z) {
  const int b = blockIdx.y;
  const int t = blockIdx.x;
  const int l0 = t * TL;
  const int tid = threadIdx.x;
  const int l = tid & 31;        // position within tile
  const int g = tid >> 5;        // row group 0..31

  __shared__ __hip_bfloat16 xt[C][TL + 2];   // 34.8 KB, stride 68 B (bank-spread)
  __shared__ float sred[32][33];             // score partials
  __shared__ float pw[TL];                   // exp(s - m_t)

  const float* xb = x + (size_t)b * C * L + l0;

  // Phase 1: stream tile (coalesced over l), accumulate partial scores, stash bf16.
  float ps = 0.f;
  #pragma unroll 4
  for (int it = 0; it < 16; ++it) {
    const int c = g + (it << 5);
    const float xv = xb[(size_t)c * L + l];
    ps += xv * cw[c];
    xt[c][l] = __float2bfloat16(xv);
  }
  sred[g][l] = ps;
  __syncthreads();

  // Wave 0: finalize 32 scores, tile-local softmax stats.
  if (tid < 64) {
    float sval = -INFINITY;
    if (tid < 32) {
      sval = 0.f;
      #pragma unroll
      for (int gg = 0; gg < 32; ++gg) sval += sred[gg][tid];
    }
    float m = sval;
    #pragma unroll
    for (int off = 32; off; off >>= 1) m = fmaxf(m, __shfl_xor(m, off));
    const float zp = (tid < 32) ? __expf(sval - m) : 0.f;
    float z = zp;
    #pragma unroll
    for (int off = 32; off; off >>= 1) z += __shfl_xor(z, off);
    if (tid < 32) pw[tid] = zp;
    if (tid == 0) {
      part_m[b * NT + t] = m;
      part_z[b * NT + t] = z;
    }
  }
  __syncthreads();

  // Phase 2: partial context from LDS tile. 2 threads per channel.
  const int c = tid >> 1;
  const int h = tid & 1;
  float acc = 0.f;
  #pragma unroll
  for (int j = 0; j < 16; ++j) {
    const int ll = h * 16 + j;
    acc += __bfloat162float(xt[c][ll]) * pw[ll];
  }
  acc += __shfl_xor(acc, 1);
  if (h == 0) part_pc[((size_t)(b * NT + t)) * C + c] = acc;
}

// ---- Tail: flash-combine partials -> context -> MLP(LN,ReLU) -> add_term ----
__global__ void k_tail(const float* __restrict__ part_pc, const float* __restrict__ part_m,
                       const float* __restrict__ part_z,
                       const float* __restrict__ w1, const float* __restrict__ b1,
                       const float* __restrict__ lnw, const float* __restrict__ lnb,
                       const float* __restrict__ w2, const float* __restrict__ b2,
                       float* __restrict__ add_term) {
  const int b = blockIdx.x;
  const int tid = threadIdx.x;   // 512 threads
  __shared__ float sm[NT], sz[NT], se[NT];
  __shared__ float sctx[C];
  __shared__ float st[PP];

  for (int t = tid; t < NT; t += 512) {
    sm[t] = part_m[b * NT + t];
    sz[t] = part_z[b * NT + t];
  }
  __syncthreads();
  float M = -INFINITY;
  #pragma unroll 8
  for (int t = 0; t < NT; ++t) M = fmaxf(M, sm[t]);
  for (int t = tid; t < NT; t += 512) se[t] = __expf(sm[t] - M);
  __syncthreads();
  float Z = 0.f;
  #pragma unroll 8
  for (int t = 0; t < NT; ++t) Z += sz[t] * se[t];
  const float Zinv = 1.f / Z;

  // context[b, tid]
  float acc = 0.f;
  const float* pp = part_pc + (size_t)b * NT * C + tid;
  #pragma unroll 4
  for (int t = 0; t < NT; ++t) acc += pp[(size_t)t * C] * se[t];
  sctx[tid] = acc * Zinv;
  __syncthreads();

  // t = w1 @ ctx + b1 (4 threads per output p)
  {
    const int p = tid >> 2;
    const int q = tid & 3;
    const float* w1r = w1 + (size_t)p * C + q * 128;
    const float* cx = &sctx[q * 128];
    float a = 0.f;
    #pragma unroll 8
    for (int cc = 0; cc < 128; ++cc) a += w1r[cc] * cx[cc];
    a += __shfl_xor(a, 1);
    a += __shfl_xor(a, 2);
    if (q == 0) st[p] = a + b1[p];
  }
  __syncthreads();

  // LayerNorm over P + ReLU (reads complete before any write)
  float tv = 0.f;
  if (tid < PP) {
    float mu = 0.f;
    #pragma unroll 8
    for (int pi = 0; pi < PP; ++pi) mu += st[pi];
    mu *= (1.f / PP);
    float var = 0.f;
    #pragma unroll 8
    for (int pi = 0; pi < PP; ++pi) { const float d = st[pi] - mu; var += d * d; }
    var *= (1.f / PP);
    tv = (st[tid] - mu) * rsqrtf(var + LN_EPS) * lnw[tid] + lnb[tid];
    tv = fmaxf(tv, 0.f);
  }
  __syncthreads();
  if (tid < PP) st[tid] = tv;
  __syncthreads();

  // add_term[c] = w2[c,:] @ t + b2[c]
  float a2 = b2[tid];
  const float* w2r = w2 + (size_t)tid * PP;
  #pragma unroll 8
  for (int pi = 0; pi < PP; ++pi) a2 += w2r[pi] * st[pi];
  add_term[b * C + tid] = a2;
}

// ---- out[b,c,:] = x[b,c,:] + add_term[b,c] ----
__global__ void k_add(const float* __restrict__ x, const float* __restrict__ at,
                      float* __restrict__ out) {
  const int bc = blockIdx.x;
  const float a = at[bc];
  const float4* xr = (const float4*)(x + (size_t)bc * L);
  float4* orow = (float4*)(out + (size_t)bc * L);
  #pragma unroll 4
  for (int i = threadIdx.x; i < L / 4; i += 256) {
    float4 v = xr[i];
    v.x += a; v.y += a; v.z += a; v.w += a;
    orow[i] = v;
  }
}

extern "C" void kernel_launch(void* const* d_in, const int* in_sizes, int n_in,
                              void* d_out, int out_size, void* d_ws, size_t ws_size,
                              hipStream_t stream) {
  const float* x   = (const float*)d_in[0];
  const float* cw  = (const float*)d_in[1];
  // d_in[2] (conv_mask_b) cancels exactly under softmax shift-invariance.
  const float* w1  = (const float*)d_in[3];
  const float* b1  = (const float*)d_in[4];
  const float* lnw = (const float*)d_in[5];
  const float* lnb = (const float*)d_in[6];
  const float* w2  = (const float*)d_in[7];
  const float* b2  = (const float*)d_in[8];
  float* out = (float*)d_out;

  char* ws = (char*)d_ws;
  float* part_pc  = (float*)ws;                                  // B*NT*C = 8 MB
  float* part_m   = (float*)(ws + (size_t)B * NT * C * 4);       // 16 KB
  float* part_z   = part_m + B * NT;                             // 16 KB
  float* add_term = part_z + B * NT;                             // 32 KB

  k_fused<<<dim3(NT, B), 1024, 0, stream>>>(x, cw, part_pc, part_m, part_z);
  k_tail<<<dim3(B), C, 0, stream>>>(part_pc, part_m, part_z,
                                    w1, b1, lnw, lnb, w2, b2, add_term);
  k_add<<<dim3(B * C), 256, 0, stream>>>(x, add_term, out);
}

// Round 3
// 153.232 us; speedup vs baseline: 1.6322x; 1.3645x over previous
//
#include <hip/hip_runtime.h>
#include <math.h>

#define B 16
#define C 512
#define L 8192
#define PP 128
#define TL 32
#define TPB 8                    // tiles per block
#define NB (L / (TL * TPB))      // 32 partial-blocks per batch
#define LN_EPS 1e-5f

typedef float fx4 __attribute__((ext_vector_type(4)));

// ---- Fused: scores + running flash softmax + partial context, all in registers. ----
// Grid (NB, B), 1024 threads. Each block sweeps 8 tiles of C x 32.
// Thread: q = tid&7 (float4 slot -> l = 4q..4q+3), r = tid>>3 (row), rows c = r+128i.
__global__ __launch_bounds__(1024, 8) void k_fused(
    const float* __restrict__ x, const float* __restrict__ cw,
    float* __restrict__ part_pc, float* __restrict__ part_m, float* __restrict__ part_z) {
  const int b = blockIdx.y;
  const int blk = blockIdx.x;
  const int tid = threadIdx.x;
  const int q = tid & 7;
  const int r = tid >> 3;
  const int lane = tid & 63;
  const int w = tid >> 6;

  __shared__ float scw[C];
  __shared__ float sred[16][32];
  __shared__ float pw[TL];
  __shared__ float s_resc;
  __shared__ float s_m, s_z;

  for (int c = tid; c < C; c += 1024) scw[c] = cw[c];
  if (tid == 0) { s_m = -INFINITY; s_z = 0.f; }

  float pc_acc[4] = {0.f, 0.f, 0.f, 0.f};
  const size_t xbase = (size_t)b * C * L;

  for (int t = 0; t < TPB; ++t) {
    const int l0 = (blk * TPB + t) * TL;
    const float4* xb4 = (const float4*)(x + xbase + l0);

    __syncthreads();   // sred/pw reuse safe; scw/s_m visible at t=0

    // Phase 1: load 4 rows x 4 l as float4, partial scores.
    float4 xv[4];
    float sp[4] = {0.f, 0.f, 0.f, 0.f};
    #pragma unroll
    for (int i = 0; i < 4; ++i) {
      const int c = r + 128 * i;
      const float4 v = xb4[(size_t)c * (L / 4) + q];
      xv[i] = v;
      const float wc = scw[c];
      sp[0] += v.x * wc; sp[1] += v.y * wc; sp[2] += v.z * wc; sp[3] += v.w * wc;
    }
    // reduce over the 8 rows within each wave (lane bits 3..5)
    #pragma unroll
    for (int m = 8; m <= 32; m <<= 1) {
      sp[0] += __shfl_xor(sp[0], m);
      sp[1] += __shfl_xor(sp[1], m);
      sp[2] += __shfl_xor(sp[2], m);
      sp[3] += __shfl_xor(sp[3], m);
    }
    if (lane < 8) {
      sred[w][4 * lane + 0] = sp[0];
      sred[w][4 * lane + 1] = sp[1];
      sred[w][4 * lane + 2] = sp[2];
      sred[w][4 * lane + 3] = sp[3];
    }
    __syncthreads();

    // Wave 0: finalize 32 scores, update running (m, z), emit pw + rescale.
    if (tid < 32) {
      float s = 0.f;
      #pragma unroll
      for (int ww = 0; ww < 16; ++ww) s += sred[ww][tid];
      float m = s;
      #pragma unroll
      for (int off = 16; off; off >>= 1) m = fmaxf(m, __shfl_xor(m, off, 32));
      const float mold = s_m;                  // read before any write
      const float mnew = fmaxf(mold, m);
      const float p = __expf(s - mnew);
      float z = p;
      #pragma unroll
      for (int off = 16; off; off >>= 1) z += __shfl_xor(z, off, 32);
      pw[tid] = p;
      if (tid == 0) {
        const float resc = __expf(mold - mnew);
        s_resc = resc;
        s_z = s_z * resc + z;
        s_m = mnew;
      }
    }
    __syncthreads();

    // Phase 2: weighted partial context from registers; reduce over q (lane bits 0..2).
    const float resc = s_resc;
    const float w0 = pw[4 * q + 0], w1 = pw[4 * q + 1];
    const float w2 = pw[4 * q + 2], w3 = pw[4 * q + 3];
    #pragma unroll
    for (int i = 0; i < 4; ++i) {
      float pv = xv[i].x * w0 + xv[i].y * w1 + xv[i].z * w2 + xv[i].w * w3;
      #pragma unroll
      for (int m = 1; m <= 4; m <<= 1) pv += __shfl_xor(pv, m);
      pc_acc[i] = pc_acc[i] * resc + pv;
    }
  }

  if (q == 0) {
    float* dst = part_pc + ((size_t)(b * NB + blk)) * C;
    #pragma unroll
    for (int i = 0; i < 4; ++i) dst[r + 128 * i] = pc_acc[i];
  }
  if (tid == 0) {
    part_m[b * NB + blk] = s_m;
    part_z[b * NB + blk] = s_z;
  }
}

// ---- Tail: flash-combine 32 partials -> context -> MLP(LN,ReLU) -> add_term ----
__global__ void k_tail(const float* __restrict__ part_pc, const float* __restrict__ part_m,
                       const float* __restrict__ part_z,
                       const float* __restrict__ w1, const float* __restrict__ b1,
                       const float* __restrict__ lnw, const float* __restrict__ lnb,
                       const float* __restrict__ w2, const float* __restrict__ b2,
                       float* __restrict__ add_term) {
  const int b = blockIdx.x;
  const int tid = threadIdx.x;   // 512 threads
  __shared__ float se[NB];
  __shared__ float sctx[C];
  __shared__ float st[PP];

  if (tid < 64) {
    const float m = (tid < NB) ? part_m[b * NB + tid] : -INFINITY;
    float M = m;
    #pragma unroll
    for (int off = 16; off; off >>= 1) M = fmaxf(M, __shfl_xor(M, off, 32));
    const float e = (tid < NB) ? __expf(m - M) : 0.f;
    float Z = (tid < NB) ? part_z[b * NB + tid] * e : 0.f;
    #pragma unroll
    for (int off = 16; off; off >>= 1) Z += __shfl_xor(Z, off, 32);
    if (tid < NB) se[tid] = e / Z;
  }
  __syncthreads();

  // context[b, tid]
  float acc = 0.f;
  const float* pp = part_pc + (size_t)b * NB * C + tid;
  #pragma unroll
  for (int t = 0; t < NB; ++t) acc += pp[(size_t)t * C] * se[t];
  sctx[tid] = acc;
  __syncthreads();

  // t = w1 @ ctx + b1 (4 threads per output p)
  {
    const int p = tid >> 2;
    const int q = tid & 3;
    const float* w1r = w1 + (size_t)p * C + q * 128;
    const float* cx = &sctx[q * 128];
    float a = 0.f;
    #pragma unroll 8
    for (int cc = 0; cc < 128; ++cc) a += w1r[cc] * cx[cc];
    a += __shfl_xor(a, 1);
    a += __shfl_xor(a, 2);
    if (q == 0) st[p] = a + b1[p];
  }
  __syncthreads();

  // LayerNorm over P + ReLU
  float tv = 0.f;
  if (tid < PP) {
    float mu = 0.f;
    #pragma unroll 8
    for (int pi = 0; pi < PP; ++pi) mu += st[pi];
    mu *= (1.f / PP);
    float var = 0.f;
    #pragma unroll 8
    for (int pi = 0; pi < PP; ++pi) { const float d = st[pi] - mu; var += d * d; }
    var *= (1.f / PP);
    tv = (st[tid] - mu) * rsqrtf(var + LN_EPS) * lnw[tid] + lnb[tid];
    tv = fmaxf(tv, 0.f);
  }
  __syncthreads();
  if (tid < PP) st[tid] = tv;
  __syncthreads();

  // add_term[c] = w2[c,:] @ t + b2[c]
  float a2 = b2[tid];
  const float* w2r = w2 + (size_t)tid * PP;
  #pragma unroll 8
  for (int pi = 0; pi < PP; ++pi) a2 += w2r[pi] * st[pi];
  add_term[b * C + tid] = a2;
}

// ---- out[b,c,:] = x[b,c,:] + add_term[b,c]; NT stores keep x resident in L3 ----
__global__ void k_add(const float* __restrict__ x, const float* __restrict__ at,
                      float* __restrict__ out) {
  const int bc = blockIdx.x;
  const float a = at[bc];
  const fx4* xr = (const fx4*)(x + (size_t)bc * L);
  fx4* orow = (fx4*)(out + (size_t)bc * L);
  #pragma unroll 4
  for (int i = threadIdx.x; i < L / 4; i += 256) {
    fx4 v = xr[i];
    v = v + a;
    __builtin_nontemporal_store(v, &orow[i]);
  }
}

extern "C" void kernel_launch(void* const* d_in, const int* in_sizes, int n_in,
                              void* d_out, int out_size, void* d_ws, size_t ws_size,
                              hipStream_t stream) {
  const float* x   = (const float*)d_in[0];
  const float* cw  = (const float*)d_in[1];
  // d_in[2] (conv_mask_b) cancels exactly under softmax shift-invariance.
  const float* w1  = (const float*)d_in[3];
  const float* b1  = (const float*)d_in[4];
  const float* lnw = (const float*)d_in[5];
  const float* lnb = (const float*)d_in[6];
  const float* w2  = (const float*)d_in[7];
  const float* b2  = (const float*)d_in[8];
  float* out = (float*)d_out;

  char* ws = (char*)d_ws;
  float* part_pc  = (float*)ws;                                // B*NB*C = 1 MB
  float* part_m   = (float*)(ws + (size_t)B * NB * C * 4);     // 2 KB
  float* part_z   = part_m + B * NB;
  float* add_term = part_z + B * NB;                           // 32 KB

  k_fused<<<dim3(NB, B), 1024, 0, stream>>>(x, cw, part_pc, part_m, part_z);
  k_tail<<<dim3(B), C, 0, stream>>>(part_pc, part_m, part_z,
                                    w1, b1, lnw, lnb, w2, b2, add_term);
  k_add<<<dim3(B * C), 256, 0, stream>>>(x, add_term, out);
}